// Round 18
// baseline (367.995 us; speedup 1.0000x reference)
//
#include <hip/hip_runtime.h>
#include <hip/hip_bf16.h>
#include <stdint.h>

typedef __attribute__((ext_vector_type(8))) short short8;
typedef __attribute__((ext_vector_type(16))) float f32x16;

#define CD 256   // channels
#define HD 512   // hidden

// ---------- helpers ----------
static __device__ __forceinline__ unsigned short f2bf(float f) {
    union { float f; unsigned int u; } cv; cv.f = f;
    unsigned int u = cv.u;
    unsigned int r = u + 0x7FFFu + ((u >> 16) & 1u);   // round-to-nearest-even
    return (unsigned short)(r >> 16);
}
static __device__ __forceinline__ unsigned int pack2(unsigned short a, unsigned short b) {
    return (unsigned int)a | ((unsigned int)b << 16);
}

// ---------- kernel 1: Wt fp32 -> bf16 ----------
__global__ void cvt_wt_kernel(const float* __restrict__ wt, unsigned short* __restrict__ out) {
    int t = blockIdx.x * blockDim.x + threadIdx.x;     // 16384 threads
    const float4* p = (const float4*)wt;
    float4 f0 = p[t * 2], f1 = p[t * 2 + 1];
    uint4 v;
    v.x = pack2(f2bf(f0.x), f2bf(f0.y));
    v.y = pack2(f2bf(f0.z), f2bf(f0.w));
    v.z = pack2(f2bf(f1.x), f2bf(f1.y));
    v.w = pack2(f2bf(f1.z), f2bf(f1.w));
    ((uint4*)out)[t] = v;
}

// ---------- kernel 2: batch (int64 OR int32) -> int32 ----------
__global__ void cvt_batch_kernel(const void* __restrict__ batch, int* __restrict__ out, int n) {
    const long long* p64 = (const long long*)batch;
    const int* p32 = (const int*)batch;
    bool is64 = ((unsigned long long)p64[n / 2 - 1]) < (1ull << 20);
    for (int i = blockIdx.x * blockDim.x + threadIdx.x; i < n; i += gridDim.x * blockDim.x)
        out[i] = is64 ? (int)p64[i] : p32[i];
}

// ---------- kernel 3: gate logits (v17 = R13 structure, register cap FIXED) ----------
// 256 rows/block, 8 waves x 32 rows. Per-wave code identical to R7 (proven
// spill-free). Wt: 16 chunks of 32h in 3 rotating 16KB LDS bufs, rolled loop +
// raw s_barrier + counted vmcnt(2) (512 thr x 2 granules staging).
// R13's (512,6) hint forced VGPR=40 -> 285MB spill (a[16] alone needs 64);
// plain (512) lets the allocator pick ~80 (R4/R7/R17 precedent). LDS 53KB ->
// 3 blocks/CU x 8 waves = up to 24 waves/CU of INDEPENDENT blocks covering
// each other's region stalls. This is the one clean TLP datapoint never taken.
__global__ __launch_bounds__(512) void gate_kernel(
    const float* __restrict__ x, const unsigned short* __restrict__ wtb,
    const float* __restrict__ bt, const float* __restrict__ wg,
    const float* __restrict__ bg, float* __restrict__ logits, int n)
{
    __shared__ __align__(16) char lds[53248];   // 48KB Wt bufs + 2KB bt + 2KB wg
    const int tid = threadIdx.x;
    const int lane = tid & 63;
    const int wid = tid >> 6;                   // 0..7
    const int l31 = lane & 31;
    const int g = lane >> 5;                    // k-half 0/1
    const long rowbase = (long)blockIdx.x * 256;

    // ---- stage bt/wg -> LDS (one float per thread per array)
    {
        *(float*)(lds + 49152 + tid * 4) = bt[tid];
        *(float*)(lds + 51200 + tid * 4) = wg[tid];
    }

    // ---- A fragments: direct global loads, cvt in-reg
    short8 a[16];
    {
        const long row = rowbase + wid * 32 + l31;
        const bool ok = row < (long)n;
        const float4* xr = (const float4*)(x + row * 256) + g * 2;
#pragma unroll
        for (int kt = 0; kt < 16; ++kt) {
            float4 f0 = ok ? xr[kt * 4]     : make_float4(0.f, 0.f, 0.f, 0.f);
            float4 f1 = ok ? xr[kt * 4 + 1] : make_float4(0.f, 0.f, 0.f, 0.f);
            __hip_bfloat162 p0 = __float22bfloat162_rn(make_float2(f0.x, f0.y));
            __hip_bfloat162 p1 = __float22bfloat162_rn(make_float2(f0.z, f0.w));
            __hip_bfloat162 p2 = __float22bfloat162_rn(make_float2(f1.x, f1.y));
            __hip_bfloat162 p3 = __float22bfloat162_rn(make_float2(f1.z, f1.w));
            union { uint4 u; short8 s; } cv;
            cv.u = make_uint4(*(unsigned int*)&p0, *(unsigned int*)&p1,
                              *(unsigned int*)&p2, *(unsigned int*)&p3);
            a[kt] = cv.s;
        }
    }

    // per-lane Wt source offsets: physical granule p holds logical (rc, (p&31)^rc)
    // 512 threads x 2 granules cover the 1024 granules of a 16KB chunk.
    int soff[2];
#pragma unroll
    for (int i = 0; i < 2; ++i) {
        int p = (wid * 2 + i) * 64 + lane;
        int rc = p >> 5;
        int gcl = (p & 31) ^ (rc & 31);
        soff[i] = rc * 512 + gcl * 16;
    }
    const char* wtbb = (const char*)wtb;

#define STAGE(c, bufoff)                                                              \
    {                                                                                 \
        const char* src = wtbb + (c) * 16384;                                         \
        char* dst = lds + (bufoff) + wid * 2048;                                      \
        _Pragma("unroll")                                                             \
        for (int i = 0; i < 2; ++i)                                                   \
            __builtin_amdgcn_global_load_lds(                                         \
                (const __attribute__((address_space(1))) unsigned int*)(src + soff[i]), \
                (__attribute__((address_space(3))) unsigned int*)(dst + i * 1024),    \
                16, 0, 0);                                                            \
    }

    // one chunk's MFMA + softplus epilogue (R7's proven form)
#define COMPUTE(c)                                                                    \
    {                                                                                 \
        const char* bb = lds + ((c) % 3) * 16384 + l31 * 512;                         \
        f32x16 acc;                                                                   \
        _Pragma("unroll")                                                             \
        for (int r = 0; r < 16; ++r) acc[r] = 0.f;                                    \
        _Pragma("unroll")                                                             \
        for (int kt = 0; kt < 16; ++kt) {                                             \
            short8 b = *(const short8*)(bb + (((kt * 2 + g) ^ l31) * 16));            \
            acc = __builtin_amdgcn_mfma_f32_32x32x16_bf16(a[kt], b, acc, 0, 0, 0);    \
        }                                                                             \
        const float btv = *(const float*)(lds + 49152 + ((c) * 32 + l31) * 4);        \
        const float wgv = *(const float*)(lds + 51200 + ((c) * 32 + l31) * 4);        \
        _Pragma("unroll")                                                             \
        for (int r = 0; r < 16; ++r) {                                                \
            float v = acc[r] + btv;                                                   \
            float sp = fmaxf(v, 0.f) + __logf(1.f + __expf(-__builtin_fabsf(v)));     \
            lp[r] = fmaf(sp, wgv, lp[r]);                                             \
        }                                                                             \
    }

    float lp[16];
#pragma unroll
    for (int r = 0; r < 16; ++r) lp[r] = 0.f;

    __syncthreads();            // bt/wg visible; all prior vmem drained (A consumed)

    STAGE(0, 0);
    STAGE(1, 16384);

#pragma unroll 1
    for (int c = 0; c < 15; ++c) {
        // outstanding here = stage(c) + stage(c+1) = 4 loads; retire stage(c) only.
        asm volatile("s_waitcnt vmcnt(2)" ::: "memory");
        __builtin_amdgcn_s_barrier();
        if (c < 14) STAGE(c + 2, ((c + 2) % 3) * 16384);
        COMPUTE(c);
    }
    // peeled last chunk: only stage(15) outstanding
    asm volatile("s_waitcnt vmcnt(0)" ::: "memory");
    __builtin_amdgcn_s_barrier();
    COMPUTE(15);
#undef COMPUTE
#undef STAGE

    // reduce over the 32 h-lanes within each half, write logits
#pragma unroll
    for (int r = 0; r < 16; ++r) {
        float v = lp[r];
        v += __shfl_xor(v, 1);
        v += __shfl_xor(v, 2);
        v += __shfl_xor(v, 4);
        v += __shfl_xor(v, 8);
        v += __shfl_xor(v, 16);
        lp[r] = v;
    }
    if (l31 == 0) {
        const float bgv = bg[0];
#pragma unroll
        for (int r = 0; r < 16; ++r) {
            long row = rowbase + wid * 32 + 4 * g + (r & 3) + 8 * (r >> 2);  // C/D layout (m74/m101)
            if (row < (long)n) logits[row] = lp[r] + bgv;
        }
    }
}

// ---------- kernel 4: per-segment stats ----------
static __device__ __forceinline__ int lower_bound(const int* __restrict__ a, int n, int v) {
    int lo = 0, hi = n;
    while (lo < hi) { int mid = (lo + hi) >> 1; if (a[mid] < v) lo = mid + 1; else hi = mid; }
    return lo;
}

__global__ void segstats_kernel(const int* __restrict__ batch, const float* __restrict__ logits,
    float* __restrict__ segmax, float* __restrict__ segrs, float* __restrict__ seginv,
    int* __restrict__ segstart, int* __restrict__ segcnt, int n)
{
    const int b = blockIdx.x;
    __shared__ int sh_se[2];
    __shared__ float sh_red[4];
    const int tid = threadIdx.x;
    if (tid == 0) {
        sh_se[0] = lower_bound(batch, n, b);
        sh_se[1] = lower_bound(batch, n, b + 1);
    }
    __syncthreads();
    const int start = sh_se[0], end = sh_se[1];
    float m = -3.4e38f;
    for (int i = start + tid; i < end; i += 256) m = fmaxf(m, logits[i]);
#pragma unroll
    for (int mk = 1; mk <= 32; mk <<= 1) m = fmaxf(m, __shfl_xor(m, mk));
    if ((tid & 63) == 0) sh_red[tid >> 6] = m;
    __syncthreads();
    m = fmaxf(fmaxf(sh_red[0], sh_red[1]), fmaxf(sh_red[2], sh_red[3]));
    float s = 0.f;
    for (int i = start + tid; i < end; i += 256) s += __expf(logits[i] - m);
#pragma unroll
    for (int mk = 1; mk <= 32; mk <<= 1) s += __shfl_xor(s, mk);
    __syncthreads();
    if ((tid & 63) == 0) sh_red[tid >> 6] = s;
    __syncthreads();
    if (tid == 0) {
        s = sh_red[0] + sh_red[1] + sh_red[2] + sh_red[3];
        const int cnt = end - start;
        segmax[b] = m;
        segrs[b] = (s > 0.f) ? (1.f / s) : 0.f;
        seginv[b] = 1.f / (float)((cnt > 0) ? cnt : 1);
        segstart[b] = start;
        segcnt[b] = cnt;
    }
}

// ---------- kernel 5: pooled output, weights computed inline via LDS stage ----------
// out[b,c] = sum_i (exp(logit_i - smax)*srs + 1/cnt) * x[i,c]
__global__ __launch_bounds__(256) void pool_kernel(const float* __restrict__ x,
    const float* __restrict__ logits, const float* __restrict__ segmax,
    const float* __restrict__ segrs, const float* __restrict__ seginv,
    const int* __restrict__ segstart, const int* __restrict__ segcnt,
    float* __restrict__ out)
{
    __shared__ float wsh[1024];
    const int b = blockIdx.x;
    const int c = threadIdx.x;
    const int start = segstart[b];
    const int cnt = segcnt[b];
    const float smax = segmax[b], srs = segrs[b], sinv = seginv[b];
    float acc = 0.f;
    for (int base = 0; base < cnt; base += 1024) {
        const int m = min(cnt - base, 1024);
        __syncthreads();
        for (int i = c; i < m; i += 256)
            wsh[i] = __expf(logits[start + base + i] - smax) * srs + sinv;
        __syncthreads();
        const float* xp = x + (size_t)(start + base) * CD + c;
        int i = 0;
        for (; i + 8 <= m; i += 8) {
            float x0 = xp[(size_t)(i+0)*CD], x1 = xp[(size_t)(i+1)*CD];
            float x2 = xp[(size_t)(i+2)*CD], x3 = xp[(size_t)(i+3)*CD];
            float x4 = xp[(size_t)(i+4)*CD], x5 = xp[(size_t)(i+5)*CD];
            float x6 = xp[(size_t)(i+6)*CD], x7 = xp[(size_t)(i+7)*CD];
            acc = fmaf(wsh[i+0],x0,fmaf(wsh[i+1],x1,fmaf(wsh[i+2],x2,fmaf(wsh[i+3],x3,acc))));
            acc = fmaf(wsh[i+4],x4,fmaf(wsh[i+5],x5,fmaf(wsh[i+6],x6,fmaf(wsh[i+7],x7,acc))));
        }
        for (; i < m; ++i) acc = fmaf(wsh[i], xp[(size_t)i*CD], acc);
    }
    out[(size_t)b * CD + c] = acc;
}

// ---------- launcher ----------
extern "C" void kernel_launch(void* const* d_in, const int* in_sizes, int n_in,
                              void* d_out, int out_size, void* d_ws, size_t ws_size,
                              hipStream_t stream)
{
    const float* x  = (const float*)d_in[0];
    const void*  batch = d_in[1];
    const float* Wt = (const float*)d_in[3];
    const float* bt = (const float*)d_in[4];
    const float* Wg = (const float*)d_in[5];
    const float* bg = (const float*)d_in[6];
    float* out = (float*)d_out;
    const int n = in_sizes[1];            // 400000
    const int nseg = out_size / CD;       // 1024

    char* ws = (char*)d_ws;
    size_t off = 0;
    unsigned short* wtb = (unsigned short*)(ws + off); off += (size_t)HD * CD * 2;
    float* logits = (float*)(ws + off); off += (size_t)n * 4;
    float* segmax = (float*)(ws + off); off += (size_t)nseg * 4;
    float* segrs  = (float*)(ws + off); off += (size_t)nseg * 4;
    float* seginv = (float*)(ws + off); off += (size_t)nseg * 4;
    int* segstart = (int*)(ws + off);   off += (size_t)nseg * 4;
    int* segcnt   = (int*)(ws + off);   off += (size_t)nseg * 4;
    int* batch32  = (int*)(ws + off);   off += (size_t)n * 4;

    hipLaunchKernelGGL(cvt_wt_kernel, dim3((HD * CD / 8) / 256), dim3(256), 0, stream, Wt, wtb);
    hipLaunchKernelGGL(cvt_batch_kernel, dim3(512), dim3(256), 0, stream, batch, batch32, n);
    hipLaunchKernelGGL(gate_kernel, dim3((n + 255) / 256), dim3(512), 0, stream,
                       x, wtb, bt, Wg, bg, logits, n);
    hipLaunchKernelGGL(segstats_kernel, dim3(nseg), dim3(256), 0, stream,
                       batch32, logits, segmax, segrs, seginv, segstart, segcnt, n);
    hipLaunchKernelGGL(pool_kernel, dim3(nseg), dim3(256), 0, stream,
                       x, logits, segmax, segrs, seginv, segstart, segcnt, out);
}

// Round 19
// 279.031 us; speedup vs baseline: 1.3188x; 1.3188x over previous
//
#include <hip/hip_runtime.h>
#include <hip/hip_bf16.h>
#include <stdint.h>

typedef __attribute__((ext_vector_type(8))) short short8;
typedef __attribute__((ext_vector_type(16))) float f32x16;

#define CD 256   // channels
#define HD 512   // hidden

// ---------- helpers ----------
static __device__ __forceinline__ unsigned short f2bf(float f) {
    union { float f; unsigned int u; } cv; cv.f = f;
    unsigned int u = cv.u;
    unsigned int r = u + 0x7FFFu + ((u >> 16) & 1u);   // round-to-nearest-even
    return (unsigned short)(r >> 16);
}
static __device__ __forceinline__ unsigned int pack2(unsigned short a, unsigned short b) {
    return (unsigned int)a | ((unsigned int)b << 16);
}

// ---------- kernel 1: fused prep -- Wt fp32->bf16 (blocks 0..63) + batch->int32 ----------
__global__ void prep_kernel(const float* __restrict__ wt, unsigned short* __restrict__ wtb,
                            const void* __restrict__ batch, int* __restrict__ b32, int n) {
    const int blk = blockIdx.x;
    if (blk < 64) {
        int t = blk * 256 + threadIdx.x;               // 16384 granules
        const float4* p = (const float4*)wt;
        float4 f0 = p[t * 2], f1 = p[t * 2 + 1];
        uint4 v;
        v.x = pack2(f2bf(f0.x), f2bf(f0.y));
        v.y = pack2(f2bf(f0.z), f2bf(f0.w));
        v.z = pack2(f2bf(f1.x), f2bf(f1.y));
        v.w = pack2(f2bf(f1.z), f2bf(f1.w));
        ((uint4*)wtb)[t] = v;
    } else {
        const long long* p64 = (const long long*)batch;
        const int* p32 = (const int*)batch;
        bool is64 = ((unsigned long long)p64[n / 2 - 1]) < (1ull << 20);
        for (int i = (blk - 64) * 256 + threadIdx.x; i < n; i += 512 * 256)
            b32[i] = is64 ? (int)p64[i] : p32[i];
    }
}

// ---------- kernel 2: gate logits (R17's best: 2x16KB bufs, + full-tile fast path) ----------
// 128 rows/block, 4 waves x 32 rows. A-frags direct from global (bf16 in-reg cvt);
// n == 400000 = 3125*128 exactly, so nearly all blocks take the unguarded path
// (drops 256 cndmask/thread). Wt: 16 chunks of 32h, 2 rotating 16KB LDS bufs,
// rolled loop + raw s_barrier + vmcnt(0) (stage issued one full region early).
__global__ __launch_bounds__(256) void gate_kernel(
    const float* __restrict__ x, const unsigned short* __restrict__ wtb,
    const float* __restrict__ bt, const float* __restrict__ wg,
    const float* __restrict__ bg, float* __restrict__ logits, int n)
{
    __shared__ __align__(16) char lds[36864];   // 2x16KB Wt bufs + 2KB bt + 2KB wg
    const int tid = threadIdx.x;
    const int lane = tid & 63;
    const int wid = tid >> 6;
    const int l31 = lane & 31;
    const int g = lane >> 5;                    // k-half 0/1
    const long rowbase = (long)blockIdx.x * 128;

    // ---- stage bt/wg -> LDS (one float2 per thread per array)
    {
        float2 b2 = ((const float2*)bt)[tid];
        float2 w2 = ((const float2*)wg)[tid];
        *(float2*)(lds + 32768 + tid * 8) = b2;
        *(float2*)(lds + 34816 + tid * 8) = w2;
    }

    // ---- A fragments: direct global loads, cvt in-reg
    short8 a[16];
    {
        const long row = rowbase + wid * 32 + l31;
        const float4* xr = (const float4*)(x + row * 256) + g * 2;
#define CVT_A(kt, F0, F1)                                                             \
        {                                                                             \
            __hip_bfloat162 p0 = __float22bfloat162_rn(make_float2((F0).x, (F0).y));  \
            __hip_bfloat162 p1 = __float22bfloat162_rn(make_float2((F0).z, (F0).w));  \
            __hip_bfloat162 p2 = __float22bfloat162_rn(make_float2((F1).x, (F1).y));  \
            __hip_bfloat162 p3 = __float22bfloat162_rn(make_float2((F1).z, (F1).w));  \
            union { uint4 u; short8 s; } cv;                                          \
            cv.u = make_uint4(*(unsigned int*)&p0, *(unsigned int*)&p1,               \
                              *(unsigned int*)&p2, *(unsigned int*)&p3);              \
            a[kt] = cv.s;                                                             \
        }
        if (rowbase + 128 <= (long)n) {         // full tile: unguarded (the hot path)
#pragma unroll
            for (int kt = 0; kt < 16; ++kt) {
                float4 f0 = xr[kt * 4];
                float4 f1 = xr[kt * 4 + 1];
                CVT_A(kt, f0, f1)
            }
        } else {
            const bool ok = row < (long)n;
#pragma unroll
            for (int kt = 0; kt < 16; ++kt) {
                float4 f0 = ok ? xr[kt * 4]     : make_float4(0.f, 0.f, 0.f, 0.f);
                float4 f1 = ok ? xr[kt * 4 + 1] : make_float4(0.f, 0.f, 0.f, 0.f);
                CVT_A(kt, f0, f1)
            }
        }
#undef CVT_A
    }

    // per-lane Wt source offsets: physical granule p holds logical (rc, (p&31)^rc)
    int soff[4];
#pragma unroll
    for (int i = 0; i < 4; ++i) {
        int p = (wid * 4 + i) * 64 + lane;
        int rc = p >> 5;
        int gcl = (p & 31) ^ (rc & 31);
        soff[i] = rc * 512 + gcl * 16;
    }
    const char* wtbb = (const char*)wtb;

#define STAGE(c, bufoff)                                                              \
    {                                                                                 \
        const char* src = wtbb + (c) * 16384;                                         \
        char* dst = lds + (bufoff) + wid * 4096;                                      \
        _Pragma("unroll")                                                             \
        for (int i = 0; i < 4; ++i)                                                   \
            __builtin_amdgcn_global_load_lds(                                         \
                (const __attribute__((address_space(1))) unsigned int*)(src + soff[i]), \
                (__attribute__((address_space(3))) unsigned int*)(dst + i * 1024),    \
                16, 0, 0);                                                            \
    }

#define COMPUTE(c)                                                                    \
    {                                                                                 \
        const char* bb = lds + ((c) & 1) * 16384 + l31 * 512;                         \
        f32x16 acc;                                                                   \
        _Pragma("unroll")                                                             \
        for (int r = 0; r < 16; ++r) acc[r] = 0.f;                                    \
        _Pragma("unroll")                                                             \
        for (int kt = 0; kt < 16; ++kt) {                                             \
            short8 b = *(const short8*)(bb + (((kt * 2 + g) ^ l31) * 16));            \
            acc = __builtin_amdgcn_mfma_f32_32x32x16_bf16(a[kt], b, acc, 0, 0, 0);    \
        }                                                                             \
        const float btv = *(const float*)(lds + 32768 + ((c) * 32 + l31) * 4);        \
        const float wgv = *(const float*)(lds + 34816 + ((c) * 32 + l31) * 4);        \
        _Pragma("unroll")                                                             \
        for (int r = 0; r < 16; ++r) {                                                \
            float v = acc[r] + btv;                                                   \
            float sp = fmaxf(v, 0.f) + __logf(1.f + __expf(-__builtin_fabsf(v)));     \
            lp[r] = fmaf(sp, wgv, lp[r]);                                             \
        }                                                                             \
    }

    float lp[16];
#pragma unroll
    for (int r = 0; r < 16; ++r) lp[r] = 0.f;

    __syncthreads();            // bt/wg visible; all prior vmem drained (A consumed)

    STAGE(0, 0);

#pragma unroll 1
    for (int c = 0; c < 16; ++c) {
        // outstanding here = stage(c) only, issued one full region earlier
        asm volatile("s_waitcnt vmcnt(0)" ::: "memory");
        __builtin_amdgcn_s_barrier();   // stage(c) visible to all; buf[(c+1)&1] free
        if (c < 15) STAGE(c + 1, ((c + 1) & 1) * 16384);
        COMPUTE(c);
    }
#undef COMPUTE
#undef STAGE

    // reduce over the 32 h-lanes within each half, write logits
#pragma unroll
    for (int r = 0; r < 16; ++r) {
        float v = lp[r];
        v += __shfl_xor(v, 1);
        v += __shfl_xor(v, 2);
        v += __shfl_xor(v, 4);
        v += __shfl_xor(v, 8);
        v += __shfl_xor(v, 16);
        lp[r] = v;
    }
    if (l31 == 0) {
        const float bgv = bg[0];
#pragma unroll
        for (int r = 0; r < 16; ++r) {
            long row = rowbase + wid * 32 + 4 * g + (r & 3) + 8 * (r >> 2);  // C/D layout (m74/m101)
            if (row < (long)n) logits[row] = lp[r] + bgv;
        }
    }
}

// ---------- kernel 3: fused segment stats + pooling ----------
// block per segment: binary-search bounds, reduce max & sum(exp) over logits,
// then pooled output out[b,c] = sum_i (exp(logit_i - m)*srs + 1/cnt) * x[i,c].
static __device__ __forceinline__ int lower_bound(const int* __restrict__ a, int n, int v) {
    int lo = 0, hi = n;
    while (lo < hi) { int mid = (lo + hi) >> 1; if (a[mid] < v) lo = mid + 1; else hi = mid; }
    return lo;
}

__global__ __launch_bounds__(256) void segpool_kernel(const float* __restrict__ x,
    const float* __restrict__ logits, const int* __restrict__ batch,
    float* __restrict__ out, int n)
{
    __shared__ float wsh[1024];
    __shared__ float sh_red[4];
    __shared__ int sh_se[2];
    const int b = blockIdx.x;
    const int tid = threadIdx.x;

    if (tid == 0) {
        sh_se[0] = lower_bound(batch, n, b);
        sh_se[1] = lower_bound(batch, n, b + 1);
    }
    __syncthreads();
    const int start = sh_se[0], end = sh_se[1];
    const int cnt = end - start;

    // ---- segment max
    float m = -3.4e38f;
    for (int i = start + tid; i < end; i += 256) m = fmaxf(m, logits[i]);
#pragma unroll
    for (int mk = 1; mk <= 32; mk <<= 1) m = fmaxf(m, __shfl_xor(m, mk));
    if ((tid & 63) == 0) sh_red[tid >> 6] = m;
    __syncthreads();
    m = fmaxf(fmaxf(sh_red[0], sh_red[1]), fmaxf(sh_red[2], sh_red[3]));
    __syncthreads();

    // ---- segment sum of exp
    float s = 0.f;
    for (int i = start + tid; i < end; i += 256) s += __expf(logits[i] - m);
#pragma unroll
    for (int mk = 1; mk <= 32; mk <<= 1) s += __shfl_xor(s, mk);
    if ((tid & 63) == 0) sh_red[tid >> 6] = s;
    __syncthreads();
    s = sh_red[0] + sh_red[1] + sh_red[2] + sh_red[3];

    const float srs = (s > 0.f) ? (1.f / s) : 0.f;
    const float sinv = 1.f / (float)((cnt > 0) ? cnt : 1);

    // ---- pooling pass (weights staged 1024 at a time in LDS)
    float acc = 0.f;
    const int c = tid;
    for (int base = 0; base < cnt; base += 1024) {
        const int mm = min(cnt - base, 1024);
        __syncthreads();
        for (int i = c; i < mm; i += 256)
            wsh[i] = __expf(logits[start + base + i] - m) * srs + sinv;
        __syncthreads();
        const float* xp = x + (size_t)(start + base) * CD + c;
        int i = 0;
        for (; i + 8 <= mm; i += 8) {
            float x0 = xp[(size_t)(i+0)*CD], x1 = xp[(size_t)(i+1)*CD];
            float x2 = xp[(size_t)(i+2)*CD], x3 = xp[(size_t)(i+3)*CD];
            float x4 = xp[(size_t)(i+4)*CD], x5 = xp[(size_t)(i+5)*CD];
            float x6 = xp[(size_t)(i+6)*CD], x7 = xp[(size_t)(i+7)*CD];
            acc = fmaf(wsh[i+0],x0,fmaf(wsh[i+1],x1,fmaf(wsh[i+2],x2,fmaf(wsh[i+3],x3,acc))));
            acc = fmaf(wsh[i+4],x4,fmaf(wsh[i+5],x5,fmaf(wsh[i+6],x6,fmaf(wsh[i+7],x7,acc))));
        }
        for (; i < mm; ++i) acc = fmaf(wsh[i], xp[(size_t)i*CD], acc);
    }
    out[(size_t)b * CD + c] = acc;
}

// ---------- launcher ----------
extern "C" void kernel_launch(void* const* d_in, const int* in_sizes, int n_in,
                              void* d_out, int out_size, void* d_ws, size_t ws_size,
                              hipStream_t stream)
{
    const float* x  = (const float*)d_in[0];
    const void*  batch = d_in[1];
    const float* Wt = (const float*)d_in[3];
    const float* bt = (const float*)d_in[4];
    const float* Wg = (const float*)d_in[5];
    const float* bg = (const float*)d_in[6];
    float* out = (float*)d_out;
    const int n = in_sizes[1];            // 400000
    const int nseg = out_size / CD;       // 1024

    char* ws = (char*)d_ws;
    size_t off = 0;
    unsigned short* wtb = (unsigned short*)(ws + off); off += (size_t)HD * CD * 2;
    float* logits = (float*)(ws + off); off += (size_t)n * 4;
    int* batch32  = (int*)(ws + off);   off += (size_t)n * 4;

    hipLaunchKernelGGL(prep_kernel, dim3(576), dim3(256), 0, stream, Wt, wtb, batch, batch32, n);
    hipLaunchKernelGGL(gate_kernel, dim3((n + 127) / 128), dim3(256), 0, stream,
                       x, wtb, bt, Wg, bg, logits, n);
    hipLaunchKernelGGL(segpool_kernel, dim3(nseg), dim3(256), 0, stream,
                       x, logits, batch32, out, n);
}

// Round 20
// 237.916 us; speedup vs baseline: 1.5467x; 1.1728x over previous
//
#include <hip/hip_runtime.h>
#include <hip/hip_bf16.h>
#include <stdint.h>

typedef __attribute__((ext_vector_type(8))) short short8;
typedef __attribute__((ext_vector_type(16))) float f32x16;

#define CD 256   // channels
#define HD 512   // hidden

// ---------- helpers ----------
static __device__ __forceinline__ unsigned short f2bf(float f) {
    union { float f; unsigned int u; } cv; cv.f = f;
    unsigned int u = cv.u;
    unsigned int r = u + 0x7FFFu + ((u >> 16) & 1u);   // round-to-nearest-even
    return (unsigned short)(r >> 16);
}
static __device__ __forceinline__ unsigned int pack2(unsigned short a, unsigned short b) {
    return (unsigned int)a | ((unsigned int)b << 16);
}

// ---------- kernel 1: fused prep -- Wt fp32->bf16 (blocks 0..63) + batch->int32 ----------
__global__ void prep_kernel(const float* __restrict__ wt, unsigned short* __restrict__ wtb,
                            const void* __restrict__ batch, int* __restrict__ b32, int n) {
    const int blk = blockIdx.x;
    if (blk < 64) {
        int t = blk * 256 + threadIdx.x;               // 16384 granules
        const float4* p = (const float4*)wt;
        float4 f0 = p[t * 2], f1 = p[t * 2 + 1];
        uint4 v;
        v.x = pack2(f2bf(f0.x), f2bf(f0.y));
        v.y = pack2(f2bf(f0.z), f2bf(f0.w));
        v.z = pack2(f2bf(f1.x), f2bf(f1.y));
        v.w = pack2(f2bf(f1.z), f2bf(f1.w));
        ((uint4*)wtb)[t] = v;
    } else {
        const long long* p64 = (const long long*)batch;
        const int* p32 = (const int*)batch;
        bool is64 = ((unsigned long long)p64[n / 2 - 1]) < (1ull << 20);
        for (int i = (blk - 64) * 256 + threadIdx.x; i < n; i += 512 * 256)
            b32[i] = is64 ? (int)p64[i] : p32[i];
    }
}

// ---------- kernel 2: gate logits (R19 best + exp2-form softplus) ----------
// 128 rows/block, 4 waves x 32 rows. A-frags direct from global (bf16 in-reg cvt);
// full-tile fast path (n = 3125*128 exactly). Wt: 16 chunks of 32h, 2 rotating
// 16KB LDS bufs, rolled loop + raw s_barrier + vmcnt(0) (stage issued one full
// region early). Softplus via sp = ln2*log2(1+2^(v*log2e)) -- raw v_exp/v_log
// builtins, drops fabs/fmax/add per value vs the |v|-split form (~15% fewer
// epilogue VALU ops). For w>24, 1+2^w == 2^w in fp32 so sp -> v exactly.
__global__ __launch_bounds__(256) void gate_kernel(
    const float* __restrict__ x, const unsigned short* __restrict__ wtb,
    const float* __restrict__ bt, const float* __restrict__ wg,
    const float* __restrict__ bg, float* __restrict__ logits, int n)
{
    __shared__ __align__(16) char lds[36864];   // 2x16KB Wt bufs + 2KB bt + 2KB wg
    const int tid = threadIdx.x;
    const int lane = tid & 63;
    const int wid = tid >> 6;
    const int l31 = lane & 31;
    const int g = lane >> 5;                    // k-half 0/1
    const long rowbase = (long)blockIdx.x * 128;

    // ---- stage bt/wg -> LDS (one float2 per thread per array)
    {
        float2 b2 = ((const float2*)bt)[tid];
        float2 w2 = ((const float2*)wg)[tid];
        *(float2*)(lds + 32768 + tid * 8) = b2;
        *(float2*)(lds + 34816 + tid * 8) = w2;
    }

    // ---- A fragments: direct global loads, cvt in-reg
    short8 a[16];
    {
        const long row = rowbase + wid * 32 + l31;
        const float4* xr = (const float4*)(x + row * 256) + g * 2;
#define CVT_A(kt, F0, F1)                                                             \
        {                                                                             \
            __hip_bfloat162 p0 = __float22bfloat162_rn(make_float2((F0).x, (F0).y));  \
            __hip_bfloat162 p1 = __float22bfloat162_rn(make_float2((F0).z, (F0).w));  \
            __hip_bfloat162 p2 = __float22bfloat162_rn(make_float2((F1).x, (F1).y));  \
            __hip_bfloat162 p3 = __float22bfloat162_rn(make_float2((F1).z, (F1).w));  \
            union { uint4 u; short8 s; } cv;                                          \
            cv.u = make_uint4(*(unsigned int*)&p0, *(unsigned int*)&p1,               \
                              *(unsigned int*)&p2, *(unsigned int*)&p3);              \
            a[kt] = cv.s;                                                             \
        }
        if (rowbase + 128 <= (long)n) {         // full tile: unguarded (the hot path)
#pragma unroll
            for (int kt = 0; kt < 16; ++kt) {
                float4 f0 = xr[kt * 4];
                float4 f1 = xr[kt * 4 + 1];
                CVT_A(kt, f0, f1)
            }
        } else {
            const bool ok = row < (long)n;
#pragma unroll
            for (int kt = 0; kt < 16; ++kt) {
                float4 f0 = ok ? xr[kt * 4]     : make_float4(0.f, 0.f, 0.f, 0.f);
                float4 f1 = ok ? xr[kt * 4 + 1] : make_float4(0.f, 0.f, 0.f, 0.f);
                CVT_A(kt, f0, f1)
            }
        }
#undef CVT_A
    }

    // per-lane Wt source offsets: physical granule p holds logical (rc, (p&31)^rc)
    int soff[4];
#pragma unroll
    for (int i = 0; i < 4; ++i) {
        int p = (wid * 4 + i) * 64 + lane;
        int rc = p >> 5;
        int gcl = (p & 31) ^ (rc & 31);
        soff[i] = rc * 512 + gcl * 16;
    }
    const char* wtbb = (const char*)wtb;

#define STAGE(c, bufoff)                                                              \
    {                                                                                 \
        const char* src = wtbb + (c) * 16384;                                         \
        char* dst = lds + (bufoff) + wid * 4096;                                      \
        _Pragma("unroll")                                                             \
        for (int i = 0; i < 4; ++i)                                                   \
            __builtin_amdgcn_global_load_lds(                                         \
                (const __attribute__((address_space(1))) unsigned int*)(src + soff[i]), \
                (__attribute__((address_space(3))) unsigned int*)(dst + i * 1024),    \
                16, 0, 0);                                                            \
    }

#define COMPUTE(c)                                                                    \
    {                                                                                 \
        const char* bb = lds + ((c) & 1) * 16384 + l31 * 512;                         \
        f32x16 acc;                                                                   \
        _Pragma("unroll")                                                             \
        for (int r = 0; r < 16; ++r) acc[r] = 0.f;                                    \
        _Pragma("unroll")                                                             \
        for (int kt = 0; kt < 16; ++kt) {                                             \
            short8 b = *(const short8*)(bb + (((kt * 2 + g) ^ l31) * 16));            \
            acc = __builtin_amdgcn_mfma_f32_32x32x16_bf16(a[kt], b, acc, 0, 0, 0);    \
        }                                                                             \
        const float btv = *(const float*)(lds + 32768 + ((c) * 32 + l31) * 4);        \
        const float wgv = *(const float*)(lds + 34816 + ((c) * 32 + l31) * 4);        \
        _Pragma("unroll")                                                             \
        for (int r = 0; r < 16; ++r) {                                                \
            float w = (acc[r] + btv) * 1.44269504f;                                   \
            float sp = 0.69314718f * __builtin_amdgcn_logf(                           \
                           1.0f + __builtin_amdgcn_exp2f(w));                         \
            lp[r] = fmaf(sp, wgv, lp[r]);                                             \
        }                                                                             \
    }

    float lp[16];
#pragma unroll
    for (int r = 0; r < 16; ++r) lp[r] = 0.f;

    __syncthreads();            // bt/wg visible; all prior vmem drained (A consumed)

    STAGE(0, 0);

#pragma unroll 1
    for (int c = 0; c < 16; ++c) {
        // outstanding here = stage(c) only, issued one full region earlier
        asm volatile("s_waitcnt vmcnt(0)" ::: "memory");
        __builtin_amdgcn_s_barrier();   // stage(c) visible to all; buf[(c+1)&1] free
        if (c < 15) STAGE(c + 1, ((c + 1) & 1) * 16384);
        COMPUTE(c);
    }
#undef COMPUTE
#undef STAGE

    // reduce over the 32 h-lanes within each half, write logits
#pragma unroll
    for (int r = 0; r < 16; ++r) {
        float v = lp[r];
        v += __shfl_xor(v, 1);
        v += __shfl_xor(v, 2);
        v += __shfl_xor(v, 4);
        v += __shfl_xor(v, 8);
        v += __shfl_xor(v, 16);
        lp[r] = v;
    }
    if (l31 == 0) {
        const float bgv = bg[0];
#pragma unroll
        for (int r = 0; r < 16; ++r) {
            long row = rowbase + wid * 32 + 4 * g + (r & 3) + 8 * (r >> 2);  // C/D layout (m74/m101)
            if (row < (long)n) logits[row] = lp[r] + bgv;
        }
    }
}

// ---------- kernel 3: fused segment stats + pooling ----------
static __device__ __forceinline__ int lower_bound(const int* __restrict__ a, int n, int v) {
    int lo = 0, hi = n;
    while (lo < hi) { int mid = (lo + hi) >> 1; if (a[mid] < v) lo = mid + 1; else hi = mid; }
    return lo;
}

__global__ __launch_bounds__(256) void segpool_kernel(const float* __restrict__ x,
    const float* __restrict__ logits, const int* __restrict__ batch,
    float* __restrict__ out, int n)
{
    __shared__ float wsh[1024];
    __shared__ float sh_red[4];
    __shared__ int sh_se[2];
    const int b = blockIdx.x;
    const int tid = threadIdx.x;

    if (tid == 0) {
        sh_se[0] = lower_bound(batch, n, b);
        sh_se[1] = lower_bound(batch, n, b + 1);
    }
    __syncthreads();
    const int start = sh_se[0], end = sh_se[1];
    const int cnt = end - start;

    // ---- segment max
    float m = -3.4e38f;
    for (int i = start + tid; i < end; i += 256) m = fmaxf(m, logits[i]);
#pragma unroll
    for (int mk = 1; mk <= 32; mk <<= 1) m = fmaxf(m, __shfl_xor(m, mk));
    if ((tid & 63) == 0) sh_red[tid >> 6] = m;
    __syncthreads();
    m = fmaxf(fmaxf(sh_red[0], sh_red[1]), fmaxf(sh_red[2], sh_red[3]));
    __syncthreads();

    // ---- segment sum of exp
    float s = 0.f;
    for (int i = start + tid; i < end; i += 256) s += __expf(logits[i] - m);
#pragma unroll
    for (int mk = 1; mk <= 32; mk <<= 1) s += __shfl_xor(s, mk);
    if ((tid & 63) == 0) sh_red[tid >> 6] = s;
    __syncthreads();
    s = sh_red[0] + sh_red[1] + sh_red[2] + sh_red[3];

    const float srs = (s > 0.f) ? (1.f / s) : 0.f;
    const float sinv = 1.f / (float)((cnt > 0) ? cnt : 1);

    // ---- pooling pass (weights staged 1024 at a time in LDS)
    float acc = 0.f;
    const int c = tid;
    for (int base = 0; base < cnt; base += 1024) {
        const int mm = min(cnt - base, 1024);
        __syncthreads();
        for (int i = c; i < mm; i += 256)
            wsh[i] = __expf(logits[start + base + i] - m) * srs + sinv;
        __syncthreads();
        const float* xp = x + (size_t)(start + base) * CD + c;
        int i = 0;
        for (; i + 8 <= mm; i += 8) {
            float x0 = xp[(size_t)(i+0)*CD], x1 = xp[(size_t)(i+1)*CD];
            float x2 = xp[(size_t)(i+2)*CD], x3 = xp[(size_t)(i+3)*CD];
            float x4 = xp[(size_t)(i+4)*CD], x5 = xp[(size_t)(i+5)*CD];
            float x6 = xp[(size_t)(i+6)*CD], x7 = xp[(size_t)(i+7)*CD];
            acc = fmaf(wsh[i+0],x0,fmaf(wsh[i+1],x1,fmaf(wsh[i+2],x2,fmaf(wsh[i+3],x3,acc))));
            acc = fmaf(wsh[i+4],x4,fmaf(wsh[i+5],x5,fmaf(wsh[i+6],x6,fmaf(wsh[i+7],x7,acc))));
        }
        for (; i < mm; ++i) acc = fmaf(wsh[i], xp[(size_t)i*CD], acc);
    }
    out[(size_t)b * CD + c] = acc;
}

// ---------- launcher ----------
extern "C" void kernel_launch(void* const* d_in, const int* in_sizes, int n_in,
                              void* d_out, int out_size, void* d_ws, size_t ws_size,
                              hipStream_t stream)
{
    const float* x  = (const float*)d_in[0];
    const void*  batch = d_in[1];
    const float* Wt = (const float*)d_in[3];
    const float* bt = (const float*)d_in[4];
    const float* Wg = (const float*)d_in[5];
    const float* bg = (const float*)d_in[6];
    float* out = (float*)d_out;
    const int n = in_sizes[1];            // 400000
    const int nseg = out_size / CD;       // 1024

    char* ws = (char*)d_ws;
    size_t off = 0;
    unsigned short* wtb = (unsigned short*)(ws + off); off += (size_t)HD * CD * 2;
    float* logits = (float*)(ws + off); off += (size_t)n * 4;
    int* batch32  = (int*)(ws + off);   off += (size_t)n * 4;

    hipLaunchKernelGGL(prep_kernel, dim3(576), dim3(256), 0, stream, Wt, wtb, batch, batch32, n);
    hipLaunchKernelGGL(gate_kernel, dim3((n + 127) / 128), dim3(256), 0, stream,
                       x, wtb, bt, Wg, bg, logits, n);
    hipLaunchKernelGGL(segpool_kernel, dim3(nseg), dim3(256), 0, stream,
                       x, logits, batch32, out, n);
}